// Round 5
// baseline (519.232 us; speedup 1.0000x reference)
//
#include <hip/hip_runtime.h>
#include <stdint.h>

// CausalSelfAttn: x(4096,2048) -> QKV proj -> 16-head causal attn -> out proj.
// R4: (1) Q/K/Vt GEMMs fused into one 1536-block launch (role-decoded) for
// occupancy; (2) all f32->bf16 cvts fused into one kernel; (3) attention
// reads V fragments direct from L2 (no V staging), K stays LDS-staged.

#define N_TOK   4096
#define D_MODEL 2048
#define N_HEADS 16
#define HD_DIM  128

typedef __attribute__((ext_vector_type(8))) short short8;
typedef __attribute__((ext_vector_type(4))) float f32x4;
typedef __attribute__((ext_vector_type(16))) float f32x16;

static __device__ __forceinline__ unsigned short f2bf(float f) {
    union { float f; uint32_t u; } v; v.f = f;
    uint32_t r = v.u + 0x7fffu + ((v.u >> 16) & 1u);
    return (unsigned short)(r >> 16);
}

static __device__ __forceinline__ float exp2fast(float x) {
    float r; asm("v_exp_f32 %0, %1" : "=v"(r) : "v"(x)); return r;
}

static __device__ __forceinline__ unsigned cvtpk_bf16(float lo, float hi) {
    unsigned r; asm("v_cvt_pk_bf16_f32 %0, %1, %2" : "=v"(r) : "v"(lo), "v"(hi));
    return r;
}

static __device__ __forceinline__ void gload_lds16(const void* g, void* l) {
    __builtin_amdgcn_global_load_lds(
        (const __attribute__((address_space(1))) void*)g,
        (__attribute__((address_space(3))) void*)l,
        16, 0, 0);
}

// ---------------- fused f32 -> bf16 conversion (all 5 tensors) -------------
#define XG  2097152   // x groups of 4
#define WG  1048576   // per-weight groups of 4
__global__ void cvt_all(const float* __restrict__ x,
                        const float* __restrict__ Wq, const float* __restrict__ Wk,
                        const float* __restrict__ Wv, const float* __restrict__ Wo,
                        unsigned short* __restrict__ xb,
                        unsigned short* __restrict__ Wqb, unsigned short* __restrict__ Wkb,
                        unsigned short* __restrict__ Wvb, unsigned short* __restrict__ Wob) {
    int i = blockIdx.x * blockDim.x + threadIdx.x;
    int stride = gridDim.x * blockDim.x;
    for (; i < XG + 4 * WG; i += stride) {
        const float* s; unsigned short* d; int j;
        if (i < XG) { s = x; d = xb; j = i; }
        else {
            int t = i - XG; int wsel = t >> 20; j = t & (WG - 1);
            if (wsel == 0)      { s = Wq; d = Wqb; }
            else if (wsel == 1) { s = Wk; d = Wkb; }
            else if (wsel == 2) { s = Wv; d = Wvb; }
            else                { s = Wo; d = Wob; }
        }
        float4 f = reinterpret_cast<const float4*>(s)[j];
        ushort4 o;
        o.x = f2bf(f.x); o.y = f2bf(f.y); o.z = f2bf(f.z); o.w = f2bf(f.w);
        reinterpret_cast<ushort4*>(d)[j] = o;
    }
}

// ---------------- GEMM core (128x128 tile, BK=64, 4 waves) -----------------
#define BM 128
#define BN 128
#define BK 64

// shared body: C(MxN tile at row0,col0) = A * B^T + bias
template<int OUT_BF16>
static __device__ __forceinline__ void gemm_body(
    const unsigned short* __restrict__ A, int lda,
    const unsigned short* __restrict__ B, int ldb,
    void* __restrict__ Cv, int ldc,
    const float* __restrict__ bias, int bias_row,
    int K, int row0, int col0,
    unsigned short* As, unsigned short* Bs)
{
    const int tid = threadIdx.x;
    const int w = tid >> 6, l = tid & 63;
    const int wr = w >> 1, wc = w & 1;
    const int l15 = l & 15, l4 = l >> 4;

    f32x4 acc[4][4] = {};

    const int srow = tid >> 3;                                    // 0..31
    const int ske  = (((tid & 7) * 16) ^ ((srow & 7) << 4)) >> 1; // elements

    for (int kt = 0; kt < K; kt += BK) {
#pragma unroll
        for (int c = 0; c < 4; ++c)
            gload_lds16(A + (size_t)(row0 + c * 32 + srow) * lda + kt + ske,
                        As + c * 2048 + w * 512);
#pragma unroll
        for (int c = 0; c < 4; ++c)
            gload_lds16(B + (size_t)(col0 + c * 32 + srow) * ldb + kt + ske,
                        Bs + c * 2048 + w * 512);
        __syncthreads();
#pragma unroll
        for (int s = 0; s < 2; ++s) {
            short8 af[4], bf[4];
#pragma unroll
            for (int mt = 0; mt < 4; ++mt) {
                int r = wr * 64 + mt * 16 + l15;
                int kb = (s * 64 + l4 * 16) ^ ((r & 7) << 4);
                af[mt] = *reinterpret_cast<const short8*>((const char*)As + r * 128 + kb);
            }
#pragma unroll
            for (int nt = 0; nt < 4; ++nt) {
                int r = wc * 64 + nt * 16 + l15;
                int kb = (s * 64 + l4 * 16) ^ ((r & 7) << 4);
                bf[nt] = *reinterpret_cast<const short8*>((const char*)Bs + r * 128 + kb);
            }
#pragma unroll
            for (int mt = 0; mt < 4; ++mt)
#pragma unroll
                for (int nt = 0; nt < 4; ++nt)
                    acc[mt][nt] = __builtin_amdgcn_mfma_f32_16x16x32_bf16(
                        af[mt], bf[nt], acc[mt][nt], 0, 0, 0);
        }
        __syncthreads();
    }

#pragma unroll
    for (int mt = 0; mt < 4; ++mt)
#pragma unroll
        for (int nt = 0; nt < 4; ++nt) {
            int col = col0 + wc * 64 + nt * 16 + l15;
#pragma unroll
            for (int r_ = 0; r_ < 4; ++r_) {
                int row = row0 + wr * 64 + mt * 16 + l4 * 4 + r_;
                float v = acc[mt][nt][r_] + (bias_row ? bias[row] : bias[col]);
                if (OUT_BF16)
                    ((unsigned short*)Cv)[(size_t)row * ldc + col] = f2bf(v);
                else
                    ((float*)Cv)[(size_t)row * ldc + col] = v;
            }
        }
}

// fused Q/K/Vt GEMM: 1536 blocks, role decoded from XCD-swizzled id.
//  blocks    0..1023 : QK  (M=4096, N=4096 -> Q cols | K cols), bias per col
//  blocks 1024..1535 : Vt  (M=2048, N=4096), bias per row
__global__ __launch_bounds__(256) void gemm_qkv(
    const unsigned short* __restrict__ xb,
    const unsigned short* __restrict__ Wqb,
    const unsigned short* __restrict__ Wkb,
    const unsigned short* __restrict__ Wvb,
    const float* __restrict__ bq, const float* __restrict__ bk,
    const float* __restrict__ bv,
    unsigned short* __restrict__ Qb, unsigned short* __restrict__ Kb,
    unsigned short* __restrict__ Vtb)
{
    __shared__ __align__(16) unsigned short As[BM * BK];
    __shared__ __align__(16) unsigned short Bs[BN * BK];

    int b = blockIdx.x;
    b = (b & 7) * 192 + (b >> 3);          // XCD-bijective (1536 % 8 == 0)

    const unsigned short *A, *B;
    unsigned short* C;
    const float* bias;
    int row0, col0, ldc, brow;
    if (b < 1024) {
        row0 = (b >> 5) * BM;
        int col = (b & 31) * BN;
        A = xb;
        if (col < 2048) { B = Wqb; C = Qb; bias = bq; col0 = col; }
        else            { B = Wkb; C = Kb; bias = bk; col0 = col - 2048; }
        ldc = 2048; brow = 0;
    } else {
        int v = b - 1024;
        row0 = (v >> 5) * BM;
        col0 = (v & 31) * BN;
        A = Wvb; B = xb; C = Vtb; bias = bv; ldc = 4096; brow = 1;
    }
    gemm_body<1>(A, D_MODEL, B, D_MODEL, C, ldc, bias, brow,
                 D_MODEL, row0, col0, As, Bs);
}

// output projection (f32 out)
__global__ __launch_bounds__(256) void gemm_proj(
    const unsigned short* __restrict__ Ob,
    const unsigned short* __restrict__ Wob,
    float* __restrict__ out, const float* __restrict__ bo)
{
    __shared__ __align__(16) unsigned short As[BM * BK];
    __shared__ __align__(16) unsigned short Bs[BN * BK];
    const int nwg = gridDim.x * gridDim.y;
    int bid = blockIdx.y * gridDim.x + blockIdx.x;
    bid = (bid & 7) * (nwg >> 3) + (bid >> 3);
    const int row0 = (bid / gridDim.x) * BM;
    const int col0 = (bid % gridDim.x) * BN;
    gemm_body<0>(Ob, D_MODEL, Wob, D_MODEL, out, D_MODEL, bo, 0,
                 D_MODEL, row0, col0, As, Bs);
}

// ---------------- causal flash attention (swapped-QK^T, 32x32) -------------
// 1024 blocks x 128 threads (2 waves, 32 q-rows each). K staged in 16KB LDS;
// V fragments read direct from global (L2-resident per XCD-head mapping).
__global__ __launch_bounds__(128) void attn_kernel(
    const unsigned short* __restrict__ Qb,
    const unsigned short* __restrict__ Kb,
    const unsigned short* __restrict__ Vtb,
    unsigned short* __restrict__ Ob)
{
    __shared__ __align__(16) unsigned short Ks[64 * 128];  // [kv][d] 256B rows
    const int tid = threadIdx.x;
    const int w = tid >> 6, l = tid & 63;
    const int l31 = l & 31, hi = l >> 5;

    // XCD-bijective remap of (head, qtile): 1024 items, 128 per XCD
    int bid = blockIdx.y * gridDim.x + blockIdx.x;
    bid = (bid & 7) * 128 + (bid >> 3);
    const int h = bid >> 6;
    const int qi = 63 - (bid & 63);             // longest-first within head
    const int q0 = qi * 64;
    const int qw = q0 + w * 32;
    const float scale2 = 0.12753139f;           // (1/sqrt(128)) * log2(e)

    short8 qreg[8];
#pragma unroll
    for (int s = 0; s < 8; ++s)
        qreg[s] = *reinterpret_cast<const short8*>(
            Qb + (size_t)(qw + l31) * D_MODEL + h * HD_DIM + s * 16 + hi * 8);

    float m = -1e30f, lsum = 0.f;
    f32x16 oacc[4] = {};

    const int nkt = qi + 1;

    const int krow_c = tid >> 4;               // 0..7 within chunk
    const int kslot  = tid & 15;

    for (int kt = 0; kt < nkt; ++kt) {
        const int kv0 = kt * 64;
        if (kt) __syncthreads();               // prev iter done reading Ks
#pragma unroll
        for (int c = 0; c < 8; ++c) {
            int row = c * 8 + krow_c;
            gload_lds16(Kb + (size_t)(kv0 + row) * D_MODEL + h * HD_DIM
                           + (kslot ^ (row & 15)) * 8,
                        Ks + c * 1024 + w * 512);
        }
        __syncthreads();                       // stage complete

        // S^T = K * Q^T : sacc[a] covers kv rows a*32..a*32+31
        f32x16 sacc[2] = {};
#pragma unroll
        for (int s = 0; s < 8; ++s)
#pragma unroll
            for (int a = 0; a < 2; ++a) {
                int row = a * 32 + l31;
                int slot = (2 * s + hi) ^ (row & 15);
                short8 kf = *reinterpret_cast<const short8*>(
                    (const char*)Ks + row * 256 + slot * 16);
                sacc[a] = __builtin_amdgcn_mfma_f32_32x32x16_bf16(
                    kf, qreg[s], sacc[a], 0, 0, 0);
            }

        // mask + row-max (raw domain); lane's scores belong to q = qw+l31
        float tmax = -1e30f;
        if (kv0 + 64 > qw) {
#pragma unroll
            for (int a = 0; a < 2; ++a)
#pragma unroll
                for (int r = 0; r < 16; ++r) {
                    int kvl = a * 32 + (r & 3) + 8 * (r >> 2) + 4 * hi;
                    float x = sacc[a][r];
                    x = (kv0 + kvl > qw + l31) ? -1e30f : x;
                    sacc[a][r] = x;
                    tmax = fmaxf(tmax, x);
                }
        } else {
#pragma unroll
            for (int a = 0; a < 2; ++a)
#pragma unroll
                for (int r = 0; r < 16; ++r) tmax = fmaxf(tmax, sacc[a][r]);
        }
        tmax = fmaxf(tmax, __shfl_xor(tmax, 32));

        // defer-max rescale (T13): thr = 8 nats = 90.2 raw units
        if (__any(tmax > m + 90.2f)) {
            float mnew = fmaxf(m, tmax);
            float alpha = exp2fast((m - mnew) * scale2);
            m = mnew;
            lsum *= alpha;
#pragma unroll
            for (int r = 0; r < 16; ++r) {
                float ar = __shfl(alpha, (r & 3) + 8 * (r >> 2) + 4 * hi, 32);
#pragma unroll
                for (int cb = 0; cb < 4; ++cb) oacc[cb][r] *= ar;
            }
        }

        const float mc = m * scale2;
        float rsum = 0.f;
#pragma unroll
        for (int a = 0; a < 2; ++a)
#pragma unroll
            for (int r = 0; r < 16; ++r) {
                float p = exp2fast(fmaf(sacc[a][r], scale2, -mc));
                sacc[a][r] = p;
                rsum += p;
            }
        rsum += __shfl_xor(rsum, 32);
        lsum += rsum;

        // PV: P A-frags via cvt_pk + permlane32_swap; V B-frags direct from L2
#pragma unroll
        for (int st = 0; st < 4; ++st) {
            const int sl = st & 1, a = st >> 1;
            unsigned A0 = cvtpk_bf16(sacc[a][8 * sl + 0], sacc[a][8 * sl + 1]);
            unsigned A1 = cvtpk_bf16(sacc[a][8 * sl + 2], sacc[a][8 * sl + 3]);
            unsigned B0 = cvtpk_bf16(sacc[a][8 * sl + 4], sacc[a][8 * sl + 5]);
            unsigned B1 = cvtpk_bf16(sacc[a][8 * sl + 6], sacc[a][8 * sl + 7]);
            asm volatile("v_permlane32_swap_b32 %0, %1" : "+v"(A0), "+v"(B0));
            asm volatile("v_permlane32_swap_b32 %0, %1" : "+v"(A1), "+v"(B1));
            union { unsigned u[4]; short8 s8; } pu;
            pu.u[0] = A0; pu.u[1] = A1; pu.u[2] = B0; pu.u[3] = B1;
#pragma unroll
            for (int cb = 0; cb < 4; ++cb) {
                short8 vf = *reinterpret_cast<const short8*>(
                    Vtb + (size_t)(h * HD_DIM + cb * 32 + l31) * N_TOK
                        + kv0 + (2 * st + hi) * 8);
                oacc[cb] = __builtin_amdgcn_mfma_f32_32x32x16_bf16(
                    pu.s8, vf, oacc[cb], 0, 0, 0);
            }
        }
    }

    // epilogue: oacc row -> q = qw + (r&3)+8*(r>>2)+4*hi ; col d = cb*32+l31
    float linv = 1.f / lsum;
#pragma unroll
    for (int r = 0; r < 16; ++r) {
        int jr = (r & 3) + 8 * (r >> 2) + 4 * hi;
        float lr = __shfl(linv, jr, 32);
        int qrow = qw + jr;
#pragma unroll
        for (int cb = 0; cb < 4; ++cb)
            Ob[(size_t)qrow * D_MODEL + h * HD_DIM + cb * 32 + l31] =
                f2bf(oacc[cb][r] * lr);
    }
}

// ---------------- launch ----------------------------------------------------
extern "C" void kernel_launch(void* const* d_in, const int* in_sizes, int n_in,
                              void* d_out, int out_size, void* d_ws, size_t ws_size,
                              hipStream_t stream) {
    const float* x  = (const float*)d_in[0];
    const float* Wq = (const float*)d_in[2];
    const float* bq = (const float*)d_in[3];
    const float* Wk = (const float*)d_in[4];
    const float* bk = (const float*)d_in[5];
    const float* Wv = (const float*)d_in[6];
    const float* bv = (const float*)d_in[7];
    const float* Wo = (const float*)d_in[8];
    const float* bo = (const float*)d_in[9];

    char* ws = (char*)d_ws;
    unsigned short* xb  = (unsigned short*)(ws);
    unsigned short* Wqb = (unsigned short*)(ws + ((size_t)16 << 20));
    unsigned short* Wkb = (unsigned short*)(ws + ((size_t)24 << 20));
    unsigned short* Wvb = (unsigned short*)(ws + ((size_t)32 << 20));
    unsigned short* Wob = (unsigned short*)(ws + ((size_t)40 << 20));
    unsigned short* Qb  = (unsigned short*)(ws + ((size_t)48 << 20));
    unsigned short* Kb  = (unsigned short*)(ws + ((size_t)64 << 20));
    unsigned short* Vtb = (unsigned short*)(ws + ((size_t)80 << 20));
    unsigned short* Ob  = (unsigned short*)(ws + ((size_t)96 << 20));

    cvt_all<<<2048, 256, 0, stream>>>(x, Wq, Wk, Wv, Wo,
                                      xb, Wqb, Wkb, Wvb, Wob);

    gemm_qkv<<<1536, 256, 0, stream>>>(xb, Wqb, Wkb, Wvb, bq, bk, bv,
                                       Qb, Kb, Vtb);

    attn_kernel<<<dim3(64, N_HEADS), 128, 0, stream>>>(Qb, Kb, Vtb, Ob);

    gemm_proj<<<dim3(D_MODEL / BN, N_TOK / BM), 256, 0, stream>>>(
        Ob, Wob, (float*)d_out, bo);
}

// Round 6
// 473.440 us; speedup vs baseline: 1.0967x; 1.0967x over previous
//
#include <hip/hip_runtime.h>
#include <stdint.h>

// CausalSelfAttn: x(4096,2048) -> QKV proj -> 16-head causal attn -> out proj.
// R5: attn = paired q-tiles (63-p then p => uniform 65 iters/block, no causal
// drain) + double-buffered K AND V LDS staging (prefetch overlaps compute).
// V restored to LDS (R4's direct-L2 V regressed: latency unhidden at 1 w/SIMD).
// Fused cvt + fused QKV GEMM kept from R4.

#define N_TOK   4096
#define D_MODEL 2048
#define N_HEADS 16
#define HD_DIM  128

typedef __attribute__((ext_vector_type(8))) short short8;
typedef __attribute__((ext_vector_type(4))) float f32x4;
typedef __attribute__((ext_vector_type(16))) float f32x16;

static __device__ __forceinline__ unsigned short f2bf(float f) {
    union { float f; uint32_t u; } v; v.f = f;
    uint32_t r = v.u + 0x7fffu + ((v.u >> 16) & 1u);
    return (unsigned short)(r >> 16);
}

static __device__ __forceinline__ float exp2fast(float x) {
    float r; asm("v_exp_f32 %0, %1" : "=v"(r) : "v"(x)); return r;
}

static __device__ __forceinline__ unsigned cvtpk_bf16(float lo, float hi) {
    unsigned r; asm("v_cvt_pk_bf16_f32 %0, %1, %2" : "=v"(r) : "v"(lo), "v"(hi));
    return r;
}

static __device__ __forceinline__ void gload_lds16(const void* g, void* l) {
    __builtin_amdgcn_global_load_lds(
        (const __attribute__((address_space(1))) void*)g,
        (__attribute__((address_space(3))) void*)l,
        16, 0, 0);
}

// ---------------- fused f32 -> bf16 conversion (all 5 tensors) -------------
#define XG  2097152   // x groups of 4
#define WG  1048576   // per-weight groups of 4
__global__ void cvt_all(const float* __restrict__ x,
                        const float* __restrict__ Wq, const float* __restrict__ Wk,
                        const float* __restrict__ Wv, const float* __restrict__ Wo,
                        unsigned short* __restrict__ xb,
                        unsigned short* __restrict__ Wqb, unsigned short* __restrict__ Wkb,
                        unsigned short* __restrict__ Wvb, unsigned short* __restrict__ Wob) {
    int i = blockIdx.x * blockDim.x + threadIdx.x;
    int stride = gridDim.x * blockDim.x;
    for (; i < XG + 4 * WG; i += stride) {
        const float* s; unsigned short* d; int j;
        if (i < XG) { s = x; d = xb; j = i; }
        else {
            int t = i - XG; int wsel = t >> 20; j = t & (WG - 1);
            if (wsel == 0)      { s = Wq; d = Wqb; }
            else if (wsel == 1) { s = Wk; d = Wkb; }
            else if (wsel == 2) { s = Wv; d = Wvb; }
            else                { s = Wo; d = Wob; }
        }
        float4 f = reinterpret_cast<const float4*>(s)[j];
        ushort4 o;
        o.x = f2bf(f.x); o.y = f2bf(f.y); o.z = f2bf(f.z); o.w = f2bf(f.w);
        reinterpret_cast<ushort4*>(d)[j] = o;
    }
}

// ---------------- GEMM core (128x128 tile, BK=64, 4 waves) -----------------
#define BM 128
#define BN 128
#define BK 64

template<int OUT_BF16>
static __device__ __forceinline__ void gemm_body(
    const unsigned short* __restrict__ A, int lda,
    const unsigned short* __restrict__ B, int ldb,
    void* __restrict__ Cv, int ldc,
    const float* __restrict__ bias, int bias_row,
    int K, int row0, int col0,
    unsigned short* As, unsigned short* Bs)
{
    const int tid = threadIdx.x;
    const int w = tid >> 6, l = tid & 63;
    const int wr = w >> 1, wc = w & 1;
    const int l15 = l & 15, l4 = l >> 4;

    f32x4 acc[4][4] = {};

    const int srow = tid >> 3;                                    // 0..31
    const int ske  = (((tid & 7) * 16) ^ ((srow & 7) << 4)) >> 1; // elements

    for (int kt = 0; kt < K; kt += BK) {
#pragma unroll
        for (int c = 0; c < 4; ++c)
            gload_lds16(A + (size_t)(row0 + c * 32 + srow) * lda + kt + ske,
                        As + c * 2048 + w * 512);
#pragma unroll
        for (int c = 0; c < 4; ++c)
            gload_lds16(B + (size_t)(col0 + c * 32 + srow) * ldb + kt + ske,
                        Bs + c * 2048 + w * 512);
        __syncthreads();
#pragma unroll
        for (int s = 0; s < 2; ++s) {
            short8 af[4], bf[4];
#pragma unroll
            for (int mt = 0; mt < 4; ++mt) {
                int r = wr * 64 + mt * 16 + l15;
                int kb = (s * 64 + l4 * 16) ^ ((r & 7) << 4);
                af[mt] = *reinterpret_cast<const short8*>((const char*)As + r * 128 + kb);
            }
#pragma unroll
            for (int nt = 0; nt < 4; ++nt) {
                int r = wc * 64 + nt * 16 + l15;
                int kb = (s * 64 + l4 * 16) ^ ((r & 7) << 4);
                bf[nt] = *reinterpret_cast<const short8*>((const char*)Bs + r * 128 + kb);
            }
#pragma unroll
            for (int mt = 0; mt < 4; ++mt)
#pragma unroll
                for (int nt = 0; nt < 4; ++nt)
                    acc[mt][nt] = __builtin_amdgcn_mfma_f32_16x16x32_bf16(
                        af[mt], bf[nt], acc[mt][nt], 0, 0, 0);
        }
        __syncthreads();
    }

#pragma unroll
    for (int mt = 0; mt < 4; ++mt)
#pragma unroll
        for (int nt = 0; nt < 4; ++nt) {
            int col = col0 + wc * 64 + nt * 16 + l15;
#pragma unroll
            for (int r_ = 0; r_ < 4; ++r_) {
                int row = row0 + wr * 64 + mt * 16 + l4 * 4 + r_;
                float v = acc[mt][nt][r_] + (bias_row ? bias[row] : bias[col]);
                if (OUT_BF16)
                    ((unsigned short*)Cv)[(size_t)row * ldc + col] = f2bf(v);
                else
                    ((float*)Cv)[(size_t)row * ldc + col] = v;
            }
        }
}

// fused Q/K/Vt GEMM: 1536 blocks, role decoded from XCD-swizzled id.
__global__ __launch_bounds__(256) void gemm_qkv(
    const unsigned short* __restrict__ xb,
    const unsigned short* __restrict__ Wqb,
    const unsigned short* __restrict__ Wkb,
    const unsigned short* __restrict__ Wvb,
    const float* __restrict__ bq, const float* __restrict__ bk,
    const float* __restrict__ bv,
    unsigned short* __restrict__ Qb, unsigned short* __restrict__ Kb,
    unsigned short* __restrict__ Vtb)
{
    __shared__ __align__(16) unsigned short As[BM * BK];
    __shared__ __align__(16) unsigned short Bs[BN * BK];

    int b = blockIdx.x;
    b = (b & 7) * 192 + (b >> 3);          // XCD-bijective (1536 % 8 == 0)

    const unsigned short *A, *B;
    unsigned short* C;
    const float* bias;
    int row0, col0, ldc, brow;
    if (b < 1024) {
        row0 = (b >> 5) * BM;
        int col = (b & 31) * BN;
        A = xb;
        if (col < 2048) { B = Wqb; C = Qb; bias = bq; col0 = col; }
        else            { B = Wkb; C = Kb; bias = bk; col0 = col - 2048; }
        ldc = 2048; brow = 0;
    } else {
        int v = b - 1024;
        row0 = (v >> 5) * BM;
        col0 = (v & 31) * BN;
        A = Wvb; B = xb; C = Vtb; bias = bv; ldc = 4096; brow = 1;
    }
    gemm_body<1>(A, D_MODEL, B, D_MODEL, C, ldc, bias, brow,
                 D_MODEL, row0, col0, As, Bs);
}

// output projection (f32 out)
__global__ __launch_bounds__(256) void gemm_proj(
    const unsigned short* __restrict__ Ob,
    const unsigned short* __restrict__ Wob,
    float* __restrict__ out, const float* __restrict__ bo)
{
    __shared__ __align__(16) unsigned short As[BM * BK];
    __shared__ __align__(16) unsigned short Bs[BN * BK];
    const int nwg = gridDim.x * gridDim.y;
    int bid = blockIdx.y * gridDim.x + blockIdx.x;
    bid = (bid & 7) * (nwg >> 3) + (bid >> 3);
    const int row0 = (bid / gridDim.x) * BM;
    const int col0 = (bid % gridDim.x) * BN;
    gemm_body<0>(Ob, D_MODEL, Wob, D_MODEL, out, D_MODEL, bo, 0,
                 D_MODEL, row0, col0, As, Bs);
}

// ---------------- causal flash attention (swapped-QK^T, 32x32) -------------
// 512 blocks x 128 threads (2 waves, 32 q-rows each). Block handles q-tiles
// (63-p) then (p): exactly 65 k-tile iterations per block (uniform). K and V
// double-buffered in 64KB LDS; prefetch of tile t+1 overlaps compute of t.
__global__ __launch_bounds__(128) void attn_kernel(
    const unsigned short* __restrict__ Qb,
    const unsigned short* __restrict__ Kb,
    const unsigned short* __restrict__ Vtb,
    unsigned short* __restrict__ Ob)
{
    __shared__ __align__(16) unsigned short Ks[2][64 * 128];  // [kv][d] 256B rows
    __shared__ __align__(16) unsigned short Vs[2][128 * 64];  // [d][kv] 128B rows
    const int tid = threadIdx.x;
    const int w = tid >> 6, l = tid & 63;
    const int l31 = l & 31, hi = l >> 5;

    // XCD-bijective remap: 512 items, 64/XCD -> 2 heads per XCD (L2-sized)
    int bid = blockIdx.x;
    bid = (bid & 7) * 64 + (bid >> 3);
    const int h = bid >> 5;
    const int p = bid & 31;
    const float scale2 = 0.12753139f;           // (1/sqrt(128)) * log2(e)

    const int krow_c = tid >> 4;                // 0..7 within chunk
    const int kslot  = tid & 15;
    const int vrow_c = tid >> 3;                // 0..15 within chunk
    const int vslot  = tid & 7;

    // stage k-tile kt into buffer buf (K: 8 chunks, V: 8 chunks)
    auto stage = [&](int kt, int buf) {
        const int kv0s = kt * 64;
#pragma unroll
        for (int c = 0; c < 8; ++c) {
            int row = c * 8 + krow_c;
            gload_lds16(Kb + (size_t)(kv0s + row) * D_MODEL + h * HD_DIM
                           + (kslot ^ (row & 15)) * 8,
                        Ks[buf] + c * 1024 + w * 512);
        }
#pragma unroll
        for (int c = 0; c < 8; ++c) {
            int row = c * 16 + vrow_c;
            gload_lds16(Vtb + (size_t)(h * HD_DIM + row) * N_TOK + kv0s
                            + (vslot ^ (row & 7)) * 8,
                        Vs[buf] + c * 1024 + w * 512);
        }
    };

#pragma unroll 1
    for (int half = 0; half < 2; ++half) {
        const int qi = half ? p : 63 - p;
        const int qw = qi * 64 + w * 32;
        const int nkt = qi + 1;

        short8 qreg[8];
#pragma unroll
        for (int s = 0; s < 8; ++s)
            qreg[s] = *reinterpret_cast<const short8*>(
                Qb + (size_t)(qw + l31) * D_MODEL + h * HD_DIM + s * 16 + hi * 8);

        float m = -1e30f, lsum = 0.f;
        f32x16 oacc[4] = {};

        stage(0, 0);
        __syncthreads();

        int cur = 0;
        for (int kt = 0; kt < nkt; ++kt) {
            if (kt + 1 < nkt) stage(kt + 1, cur ^ 1);
            const int kv0 = kt * 64;

            // S^T = K * Q^T : sacc[a] covers kv rows a*32..a*32+31
            f32x16 sacc[2] = {};
#pragma unroll
            for (int s = 0; s < 8; ++s)
#pragma unroll
                for (int a = 0; a < 2; ++a) {
                    int row = a * 32 + l31;
                    int slot = (2 * s + hi) ^ (row & 15);
                    short8 kf = *reinterpret_cast<const short8*>(
                        (const char*)Ks[cur] + row * 256 + slot * 16);
                    sacc[a] = __builtin_amdgcn_mfma_f32_32x32x16_bf16(
                        kf, qreg[s], sacc[a], 0, 0, 0);
                }

            // mask + row-max (raw domain); lane's scores belong to q = qw+l31
            float tmax = -1e30f;
            if (kv0 + 64 > qw) {
#pragma unroll
                for (int a = 0; a < 2; ++a)
#pragma unroll
                    for (int r = 0; r < 16; ++r) {
                        int kvl = a * 32 + (r & 3) + 8 * (r >> 2) + 4 * hi;
                        float x = sacc[a][r];
                        x = (kv0 + kvl > qw + l31) ? -1e30f : x;
                        sacc[a][r] = x;
                        tmax = fmaxf(tmax, x);
                    }
            } else {
#pragma unroll
                for (int a = 0; a < 2; ++a)
#pragma unroll
                    for (int r = 0; r < 16; ++r) tmax = fmaxf(tmax, sacc[a][r]);
            }
            tmax = fmaxf(tmax, __shfl_xor(tmax, 32));

            // defer-max rescale (T13): thr = 8 nats = 90.2 raw units
            if (__any(tmax > m + 90.2f)) {
                float mnew = fmaxf(m, tmax);
                float alpha = exp2fast((m - mnew) * scale2);
                m = mnew;
                lsum *= alpha;
#pragma unroll
                for (int r = 0; r < 16; ++r) {
                    float ar = __shfl(alpha, (r & 3) + 8 * (r >> 2) + 4 * hi, 32);
#pragma unroll
                    for (int cb = 0; cb < 4; ++cb) oacc[cb][r] *= ar;
                }
            }

            const float mc = m * scale2;
            float rsum = 0.f;
#pragma unroll
            for (int a = 0; a < 2; ++a)
#pragma unroll
                for (int r = 0; r < 16; ++r) {
                    float pe = exp2fast(fmaf(sacc[a][r], scale2, -mc));
                    sacc[a][r] = pe;
                    rsum += pe;
                }
            rsum += __shfl_xor(rsum, 32);
            lsum += rsum;

            // PV: P A-frags via cvt_pk + permlane32_swap; V B-frags from LDS
#pragma unroll
            for (int st = 0; st < 4; ++st) {
                const int sl = st & 1, a = st >> 1;
                unsigned A0 = cvtpk_bf16(sacc[a][8 * sl + 0], sacc[a][8 * sl + 1]);
                unsigned A1 = cvtpk_bf16(sacc[a][8 * sl + 2], sacc[a][8 * sl + 3]);
                unsigned B0 = cvtpk_bf16(sacc[a][8 * sl + 4], sacc[a][8 * sl + 5]);
                unsigned B1 = cvtpk_bf16(sacc[a][8 * sl + 6], sacc[a][8 * sl + 7]);
                asm volatile("v_permlane32_swap_b32 %0, %1" : "+v"(A0), "+v"(B0));
                asm volatile("v_permlane32_swap_b32 %0, %1" : "+v"(A1), "+v"(B1));
                union { unsigned u[4]; short8 s8; } pu;
                pu.u[0] = A0; pu.u[1] = A1; pu.u[2] = B0; pu.u[3] = B1;
#pragma unroll
                for (int cb = 0; cb < 4; ++cb) {
                    int row = cb * 32 + l31;
                    int slot = (2 * st + hi) ^ (row & 7);
                    short8 vf = *reinterpret_cast<const short8*>(
                        (const char*)Vs[cur] + row * 128 + slot * 16);
                    oacc[cb] = __builtin_amdgcn_mfma_f32_32x32x16_bf16(
                        pu.s8, vf, oacc[cb], 0, 0, 0);
                }
            }
            __syncthreads();   // prefetch vmcnt drained; all waves done with buf
            cur ^= 1;
        }

        // epilogue: oacc row -> q = qw + (r&3)+8*(r>>2)+4*hi ; d = cb*32+l31
        float linv = 1.f / lsum;
#pragma unroll
        for (int r = 0; r < 16; ++r) {
            int jr = (r & 3) + 8 * (r >> 2) + 4 * hi;
            float lr = __shfl(linv, jr, 32);
            int qrow = qw + jr;
#pragma unroll
            for (int cb = 0; cb < 4; ++cb)
                Ob[(size_t)qrow * D_MODEL + h * HD_DIM + cb * 32 + l31] =
                    f2bf(oacc[cb][r] * lr);
        }
    }
}

// ---------------- launch ----------------------------------------------------
extern "C" void kernel_launch(void* const* d_in, const int* in_sizes, int n_in,
                              void* d_out, int out_size, void* d_ws, size_t ws_size,
                              hipStream_t stream) {
    const float* x  = (const float*)d_in[0];
    const float* Wq = (const float*)d_in[2];
    const float* bq = (const float*)d_in[3];
    const float* Wk = (const float*)d_in[4];
    const float* bk = (const float*)d_in[5];
    const float* Wv = (const float*)d_in[6];
    const float* bv = (const float*)d_in[7];
    const float* Wo = (const float*)d_in[8];
    const float* bo = (const float*)d_in[9];

    char* ws = (char*)d_ws;
    unsigned short* xb  = (unsigned short*)(ws);
    unsigned short* Wqb = (unsigned short*)(ws + ((size_t)16 << 20));
    unsigned short* Wkb = (unsigned short*)(ws + ((size_t)24 << 20));
    unsigned short* Wvb = (unsigned short*)(ws + ((size_t)32 << 20));
    unsigned short* Wob = (unsigned short*)(ws + ((size_t)40 << 20));
    unsigned short* Qb  = (unsigned short*)(ws + ((size_t)48 << 20));
    unsigned short* Kb  = (unsigned short*)(ws + ((size_t)64 << 20));
    unsigned short* Vtb = (unsigned short*)(ws + ((size_t)80 << 20));
    unsigned short* Ob  = (unsigned short*)(ws + ((size_t)96 << 20));

    cvt_all<<<2048, 256, 0, stream>>>(x, Wq, Wk, Wv, Wo,
                                      xb, Wqb, Wkb, Wvb, Wob);

    gemm_qkv<<<1536, 256, 0, stream>>>(xb, Wqb, Wkb, Wvb, bq, bk, bv,
                                       Qb, Kb, Vtb);

    attn_kernel<<<512, 128, 0, stream>>>(Qb, Kb, Vtb, Ob);

    gemm_proj<<<dim3(D_MODEL / BN, N_TOK / BM), 256, 0, stream>>>(
        Ob, Wob, (float*)d_out, bo);
}